// Round 1
// baseline (325.443 us; speedup 1.0000x reference)
//
#include <hip/hip_runtime.h>

#define NEG_SLOPE 0.01f
#define ETA 0.5f
#define NEG_BIG -3.402823466e38f
#define LOG2E 1.4426950408889634f
#define PCHUNK 4096   // edges per partition block
#define CAP 10240     // per-coarse-bucket capacity (mean 8192 + 22 sigma)

typedef _Float16 half2v __attribute__((ext_vector_type(2)));

#if defined(__has_builtin)
#if __has_builtin(__builtin_amdgcn_fdot2)
#define HAVE_FDOT2 1
#endif
#if __has_builtin(__builtin_amdgcn_exp2f)
#define HAVE_EXP2 1
#endif
#if __has_builtin(__builtin_amdgcn_update_dpp)
#define HAVE_DPP 1
#endif
#endif

__device__ __forceinline__ float fdot2(half2v a, half2v b, float c) {
#ifdef HAVE_FDOT2
  return __builtin_amdgcn_fdot2(a, b, c, false);
#else
  return (float)a[0] * (float)b[0] + (float)a[1] * (float)b[1] + c;
#endif
}

__device__ __forceinline__ unsigned pack2(float x, float y) {
  half2v h = {( _Float16)x, (_Float16)y};
  return __builtin_bit_cast(unsigned, h);
}

// exp2 (inputs are pre-scaled into log2 domain)
__device__ __forceinline__ float fexp2(float x) {
#ifdef HAVE_EXP2
  return __builtin_amdgcn_exp2f(x);
#else
  return __expf(x * 0.6931471805599453f);
#endif
}

// Sum across a 16-lane row; every lane gets the total. DPP rotate-accumulate
// (VALU pipe, no LDS) with shfl fallback.
__device__ __forceinline__ float rowsum16(float x) {
#ifdef HAVE_DPP
  x += __builtin_bit_cast(float, __builtin_amdgcn_update_dpp(
         0, __builtin_bit_cast(int, x), 0x121, 0xf, 0xf, true)); // row_ror:1
  x += __builtin_bit_cast(float, __builtin_amdgcn_update_dpp(
         0, __builtin_bit_cast(int, x), 0x122, 0xf, 0xf, true)); // row_ror:2
  x += __builtin_bit_cast(float, __builtin_amdgcn_update_dpp(
         0, __builtin_bit_cast(int, x), 0x124, 0xf, 0xf, true)); // row_ror:4
  x += __builtin_bit_cast(float, __builtin_amdgcn_update_dpp(
         0, __builtin_bit_cast(int, x), 0x128, 0xf, 0xf, true)); // row_ror:8
  return x;
#else
  x += __shfl_xor(x, 1);
  x += __shfl_xor(x, 2);
  x += __shfl_xor(x, 4);
  x += __shfl_xor(x, 8);
  return x;
#endif
}

// ---- prep: node dots af/bf (pre-scaled by log2e) + interleaved f16 record ----
__device__ __forceinline__ void prep_body(const float* __restrict__ h,
                                          const float* __restrict__ tax,
                                          const float* __restrict__ whw,
                                          float* __restrict__ af, float* __restrict__ bf,
                                          uint4* __restrict__ rec, int n, int blk) {
  int gid = blk * 256 + (int)threadIdx.x;
  int node = gid >> 4, lane = gid & 15;
  if (node >= n) return;
  float4 x  = ((const float4*)(h + (size_t)node * 64))[lane];
  float4 tx = ((const float4*)(tax + (size_t)node * 64))[lane];
  float4 wa = ((const float4*)whw)[lane];
  float4 wb = ((const float4*)(whw + 64))[lane];
  uint4 r;
  r.x = pack2(tx.x, tx.y);
  r.y = pack2(tx.z, tx.w);
  r.z = pack2(x.x, x.y);
  r.w = pack2(x.z, x.w);
  rec[((size_t)node << 4) + lane] = r;
  float pa = x.x * wa.x + x.y * wa.y + x.z * wa.z + x.w * wa.w;
  float pb = x.x * wb.x + x.y * wb.y + x.z * wb.z + x.w * wb.w;
#pragma unroll
  for (int o = 8; o; o >>= 1) {
    pa += __shfl_xor(pa, o);
    pb += __shfl_xor(pb, o);
  }
  // leaky_relu(c*x) == c*leaky_relu(x) for c>0, so pre-scaling into the
  // exp2 domain is exact w.r.t. the lrelu and the softmax ratios.
  if (lane == 0) { af[node] = pa * LOG2E; bf[node] = pb * LOG2E; }
}

// ---- coarse partition by bucket = dst>>9 (unchanged math) ----
__device__ __forceinline__ void part_body(const int* __restrict__ src,
                                          const int* __restrict__ dst,
                                          int* __restrict__ gcur, int* __restrict__ pck,
                                          int ne, int blk) {
  __shared__ int s_hist[256];
  __shared__ int s_res[256];
  __shared__ int s_cur[256];
  int t = threadIdx.x;
  int base = blk * PCHUNK;
  int cnt = ne - base; if (cnt > PCHUNK) cnt = PCHUNK;
  s_hist[t] = 0;
  __syncthreads();
  for (int i = t; i < cnt; i += 256)
    atomicAdd(&s_hist[dst[base + i] >> 9], 1);
  __syncthreads();
  int v = s_hist[t];
  if (v > 0) s_res[t] = atomicAdd(&gcur[t], v);
  s_cur[t] = 0;
  __syncthreads();
  for (int i = t; i < cnt; i += 256) {
    int d = dst[base + i];
    int r = d >> 9;
    int g = s_res[r] + atomicAdd(&s_cur[r], 1);
    if (g < CAP)
      pck[r * CAP + g] = (src[base + i] << 9) | (d & 511);
  }
}

// Fused prep + partition. Partition blocks FIRST so the latency/atomic-bound
// partition overlaps with prep's BW-bound streaming. gcur zeroed by memset.
__global__ void k_prep_part(const float* __restrict__ h, const float* __restrict__ tax,
                            const float* __restrict__ whw,
                            float* __restrict__ af, float* __restrict__ bf,
                            uint4* __restrict__ rec,
                            const int* __restrict__ src, const int* __restrict__ dst,
                            int* __restrict__ gcur, int* __restrict__ pck,
                            int n, int ne, int npart) {
  int b = (int)blockIdx.x;
  if (b < npart) part_body(src, dst, gcur, pck, ne, b);
  else           prep_body(h, tax, whw, af, bf, rec, n, b - npart);
}

// One block per coarse bucket: exact CSR via LDS hist + scan (unchanged).
__global__ void k_finesort(const int* __restrict__ pck, const int* __restrict__ gcur,
                           int* __restrict__ off, int* __restrict__ srcs,
                           int n, int nb) {
  __shared__ int s_hist[512];
  __shared__ int s_scan[512];
  __shared__ int s_pair[256];
  __shared__ int s_red[256];
  int b = blockIdx.x;
  int t = threadIdx.x;
  int cnt = gcur[b];
  int gbase = b * CAP;
  s_red[t] = (t < b && t < nb) ? gcur[t] : 0;
  s_hist[t] = 0; s_hist[t + 256] = 0;
  __syncthreads();
  for (int s = 128; s; s >>= 1) {
    if (t < s) s_red[t] += s_red[t + s];
    __syncthreads();
  }
  int base = s_red[0];
  for (int i = t; i < cnt; i += 256)
    atomicAdd(&s_hist[pck[gbase + i] & 511], 1);
  __syncthreads();
  int c0 = s_hist[2 * t], c1 = s_hist[2 * t + 1];
  int v = c0 + c1;
  s_pair[t] = v;
  __syncthreads();
  for (int s = 1; s < 256; s <<= 1) {
    int a = (t >= s) ? s_pair[t - s] : 0;
    __syncthreads();
    s_pair[t] += a;
    __syncthreads();
  }
  int pex = s_pair[t] - v;
  s_scan[2 * t] = pex;
  s_scan[2 * t + 1] = pex + c0;
  __syncthreads();
  int d0 = (b << 9) + 2 * t;
  if (d0 < n) off[d0] = base + s_scan[2 * t];
  if (d0 + 1 < n) off[d0 + 1] = base + s_scan[2 * t + 1];
  if (b == nb - 1 && t == 0) off[n] = base + cnt;
  s_hist[2 * t] = s_scan[2 * t];
  s_hist[2 * t + 1] = s_scan[2 * t + 1];
  __syncthreads();
  for (int i = t; i < cnt; i += 256) {
    int p = pck[gbase + i];
    int rank = atomicAdd(&s_hist[p & 511], 1);
    srcs[base + rank] = p >> 9;
  }
}

// One 16-lane GROUP per dst node (4 nodes/wave): sf/st/mt are group-uniform,
// zf/zt finalize in-lane -> no cross-group butterfly merge. DPP dot-reduce,
// exp2-domain softmax, +1-deep software pipeline on srcs/rec/af.
__launch_bounds__(256)
__global__ void k_fused(const uint4* __restrict__ rec,
                        const float* __restrict__ af, const float* __restrict__ bf,
                        const int* __restrict__ off, const int* __restrict__ srcs,
                        unsigned short* __restrict__ z, int n) {
  int d = (int)((blockIdx.x * blockDim.x + threadIdx.x) >> 4);
  int q = threadIdx.x & 15;
  if (d >= n) return;
  uint4 rd = rec[((size_t)d << 4) + q];
  half2v d01 = __builtin_bit_cast(half2v, rd.x);
  half2v d23 = __builtin_bit_cast(half2v, rd.y);
  float bfd = bf[d];
  int beg = off[d], end = off[d + 1];
  float sf = 0.f, st = 0.f, mt = NEG_BIG;
  float zf0 = 0.f, zf1 = 0.f, zf2 = 0.f, zf3 = 0.f;
  float zt0 = 0.f, zt1 = 0.f, zt2 = 0.f, zt3 = 0.f;
  int s = (beg < end) ? srcs[beg] : 0;
  uint4 r = rec[((size_t)s << 4) + q];  // harmless dummy when node has no edges
  float afs = af[s];
  for (int i = beg; i < end; ++i) {
    uint4 rc = r;
    float afc = afs;
    if (i + 1 < end) {  // prefetch next edge's record one iteration ahead
      int sn = srcs[i + 1];
      r = rec[((size_t)sn << 4) + q];
      afs = af[sn];
    }
    half2v t01 = __builtin_bit_cast(half2v, rc.x);
    half2v t23 = __builtin_bit_cast(half2v, rc.y);
    half2v h01 = __builtin_bit_cast(half2v, rc.z);
    half2v h23 = __builtin_bit_cast(half2v, rc.w);
    float p = fdot2(t23, d23, fdot2(t01, d01, 0.f)) * LOG2E;
    p = rowsum16(p);
    float wf = afc + bfd;             // already log2-scaled
    wf = (wf > 0.f) ? wf : NEG_SLOPE * wf;
    float ef = fexp2(wf);
    sf += ef;
    zf0 = fmaf((float)h01[0], ef, zf0);
    zf1 = fmaf((float)h01[1], ef, zf1);
    zf2 = fmaf((float)h23[0], ef, zf2);
    zf3 = fmaf((float)h23[1], ef, zf3);
    float pm = p - mt;
    if (pm > 60.f) {                  // rare: first edge / new-max-by-far
      float sc = fexp2(-pm);          // ==0 when mt==NEG_BIG
      st *= sc;
      zt0 *= sc; zt1 *= sc; zt2 *= sc; zt3 *= sc;
      mt = p; pm = 0.f;
    }
    float et = fexp2(pm);
    st += et;
    zt0 = fmaf((float)h01[0], et, zt0);
    zt1 = fmaf((float)h01[1], et, zt1);
    zt2 = fmaf((float)h23[0], et, zt2);
    zt3 = fmaf((float)h23[1], et, zt3);
  }
  float4 zv = make_float4(0.f, 0.f, 0.f, 0.f);
  if (end > beg) {
    float rf = ETA / sf, rt = (1.f - ETA) / st;
    zv.x = rf * zf0 + rt * zt0;
    zv.y = rf * zf1 + rt * zt1;
    zv.z = rf * zf2 + rt * zt2;
    zv.w = rf * zf3 + rt * zt3;
  }
  uint2 zo;
  zo.x = pack2(zv.x, zv.y);
  zo.y = pack2(zv.z, zv.w);
  ((uint2*)(z + (size_t)d * 64))[q] = zo;
}

// out[n][j] = sum_k z[n][k] * W[j][k] + b[j], z in f16.
__launch_bounds__(256)
__global__ void k_out_gemm(const unsigned short* __restrict__ z,
                           const float* __restrict__ W,
                           const float* __restrict__ b, float* __restrict__ out, int n) {
  int t = threadIdx.x;
  int j = t & 63, nl = t >> 6;
  float wreg[64];
#pragma unroll
  for (int i = 0; i < 16; ++i)
    ((float4*)wreg)[i] = ((const float4*)(W + (size_t)j * 64))[i];
  float bias = b[j];
  int stride = gridDim.x * 4;
  for (int node = blockIdx.x * 4 + nl; node < n; node += stride) {
    float zv = (float)__builtin_bit_cast(_Float16, z[(size_t)node * 64 + j]);
    float acc = bias;
#pragma unroll
    for (int k = 0; k < 64; ++k)
      acc += __shfl(zv, k) * wreg[k];
    out[(size_t)node * 64 + j] = acc;
  }
}

extern "C" void kernel_launch(void* const* d_in, const int* in_sizes, int n_in,
                              void* d_out, int out_size, void* d_ws, size_t ws_size,
                              hipStream_t stream) {
  const float* h   = (const float*)d_in[0];
  const float* tax = (const float*)d_in[1];
  const int*   src = (const int*)d_in[2];
  const int*   dst = (const int*)d_in[3];
  const float* whw = (const float*)d_in[4];
  const float* Ww  = (const float*)d_in[5];
  const float* Wb  = (const float*)d_in[6];
  float* out = (float*)d_out;
  int n  = in_sizes[0] / 64;
  int ne = in_sizes[2];
  int nb = (n + 511) >> 9;  // coarse buckets (196 for n=100k); nb<=256

  // Workspace layout (4-byte words; rec aligned to 16 B):
  float* af   = (float*)d_ws;               // n
  float* bf   = af + n;                     // n
  int*   off  = (int*)(bf + n);             // n+2
  int*   srcs = off + n + 2;                // ne
  int*   gcur = srcs + ne;                  // 256
  size_t w = (size_t)(2 * n) + (n + 2) + ne + 256;
  w = (w + 3) & ~(size_t)3;                 // 16B-align
  unsigned short* z = (unsigned short*)((int*)d_ws + w);  // n*64 u16
  uint4* rec = (uint4*)(z + (size_t)n * 64);              // n*16 uint4
  // Packed sort plane aliases z (consumed by k_finesort before z written):
  int* pck = (int*)z;                       // nb*CAP*4B (8MB) <= n*128B (12.8MB)

  int nprep = (n * 16 + 255) / 256;
  int npart = (ne + PCHUNK - 1) / PCHUNK;
  int bw    = (n + 15) / 16;

  hipMemsetAsync(gcur, 0, 256 * sizeof(int), stream);
  k_prep_part<<<npart + nprep, 256, 0, stream>>>(h, tax, whw, af, bf, rec,
                                                 src, dst, gcur, pck, n, ne, npart);
  k_finesort<<<nb, 256, 0, stream>>>(pck, gcur, off, srcs, n, nb);
  k_fused<<<bw, 256, 0, stream>>>(rec, af, bf, off, srcs, z, n);
  k_out_gemm<<<1024, 256, 0, stream>>>(z, Ww, Wb, out, n);
}

// Round 2
// 319.634 us; speedup vs baseline: 1.0182x; 1.0182x over previous
//
#include <hip/hip_runtime.h>

#define NEG_SLOPE 0.01f
#define ETA 0.5f
#define NEG_BIG -3.402823466e38f
#define LOG2E 1.4426950408889634f
#define PCHUNK 4096   // edges per partition block
#define CAP 10240     // per-coarse-bucket capacity (mean 8192 + 22 sigma)

typedef _Float16 half2v __attribute__((ext_vector_type(2)));

#if defined(__has_builtin)
#if __has_builtin(__builtin_amdgcn_fdot2)
#define HAVE_FDOT2 1
#endif
#if __has_builtin(__builtin_amdgcn_exp2f)
#define HAVE_EXP2 1
#endif
#if __has_builtin(__builtin_amdgcn_update_dpp)
#define HAVE_DPP 1
#endif
#endif

__device__ __forceinline__ float fdot2(half2v a, half2v b, float c) {
#ifdef HAVE_FDOT2
  return __builtin_amdgcn_fdot2(a, b, c, false);
#else
  return (float)a[0] * (float)b[0] + (float)a[1] * (float)b[1] + c;
#endif
}

__device__ __forceinline__ unsigned pack2(float x, float y) {
  half2v h = {( _Float16)x, (_Float16)y};
  return __builtin_bit_cast(unsigned, h);
}

// exp2 (inputs are pre-scaled into log2 domain)
__device__ __forceinline__ float fexp2(float x) {
#ifdef HAVE_EXP2
  return __builtin_amdgcn_exp2f(x);
#else
  return __expf(x * 0.6931471805599453f);
#endif
}

// Interleaved dual 16-lane row-sum (VALU pipe, no LDS); interleaving the two
// chains hides the DPP->add dependency latency.
__device__ __forceinline__ void rowsum16x2(float& x, float& y) {
#ifdef HAVE_DPP
#define DPPADD(v, ctl)                                                        \
  v += __builtin_bit_cast(float, __builtin_amdgcn_update_dpp(                 \
         0, __builtin_bit_cast(int, v), ctl, 0xf, 0xf, true))
  DPPADD(x, 0x121); DPPADD(y, 0x121);   // row_ror:1
  DPPADD(x, 0x122); DPPADD(y, 0x122);   // row_ror:2
  DPPADD(x, 0x124); DPPADD(y, 0x124);   // row_ror:4
  DPPADD(x, 0x128); DPPADD(y, 0x128);   // row_ror:8
#undef DPPADD
#else
#pragma unroll
  for (int o = 1; o < 16; o <<= 1) {
    x += __shfl_xor(x, o);
    y += __shfl_xor(y, o);
  }
#endif
}

// ---- prep: node dots af/bf (pre-scaled by log2e) + interleaved f16 record ----
__device__ __forceinline__ void prep_body(const float* __restrict__ h,
                                          const float* __restrict__ tax,
                                          const float* __restrict__ whw,
                                          float* __restrict__ af, float* __restrict__ bf,
                                          uint4* __restrict__ rec, int n, int blk) {
  int gid = blk * 256 + (int)threadIdx.x;
  int node = gid >> 4, lane = gid & 15;
  if (node >= n) return;
  float4 x  = ((const float4*)(h + (size_t)node * 64))[lane];
  float4 tx = ((const float4*)(tax + (size_t)node * 64))[lane];
  float4 wa = ((const float4*)whw)[lane];
  float4 wb = ((const float4*)(whw + 64))[lane];
  uint4 r;
  r.x = pack2(tx.x, tx.y);
  r.y = pack2(tx.z, tx.w);
  r.z = pack2(x.x, x.y);
  r.w = pack2(x.z, x.w);
  rec[((size_t)node << 4) + lane] = r;
  float pa = x.x * wa.x + x.y * wa.y + x.z * wa.z + x.w * wa.w;
  float pb = x.x * wb.x + x.y * wb.y + x.z * wb.z + x.w * wb.w;
#pragma unroll
  for (int o = 8; o; o >>= 1) {
    pa += __shfl_xor(pa, o);
    pb += __shfl_xor(pb, o);
  }
  // leaky_relu(c*x) == c*leaky_relu(x) for c>0, so pre-scaling into the
  // exp2 domain is exact w.r.t. the lrelu and the softmax ratios.
  if (lane == 0) { af[node] = pa * LOG2E; bf[node] = pb * LOG2E; }
}

// ---- coarse partition by bucket = dst>>9 ----
__device__ __forceinline__ void part_body(const int* __restrict__ src,
                                          const int* __restrict__ dst,
                                          int* __restrict__ gcur, int* __restrict__ pck,
                                          int ne, int blk) {
  __shared__ int s_hist[256];
  __shared__ int s_res[256];
  __shared__ int s_cur[256];
  int t = threadIdx.x;
  int base = blk * PCHUNK;
  int cnt = ne - base; if (cnt > PCHUNK) cnt = PCHUNK;
  s_hist[t] = 0;
  __syncthreads();
  for (int i = t; i < cnt; i += 256)
    atomicAdd(&s_hist[dst[base + i] >> 9], 1);
  __syncthreads();
  int v = s_hist[t];
  if (v > 0) s_res[t] = atomicAdd(&gcur[t], v);
  s_cur[t] = 0;
  __syncthreads();
  for (int i = t; i < cnt; i += 256) {
    int d = dst[base + i];
    int r = d >> 9;
    int g = s_res[r] + atomicAdd(&s_cur[r], 1);
    if (g < CAP)
      pck[r * CAP + g] = (src[base + i] << 9) | (d & 511);
  }
}

// Fused prep + partition. Partition blocks FIRST so the latency/atomic-bound
// partition overlaps with prep's BW-bound streaming. gcur zeroed by memset.
__global__ void k_prep_part(const float* __restrict__ h, const float* __restrict__ tax,
                            const float* __restrict__ whw,
                            float* __restrict__ af, float* __restrict__ bf,
                            uint4* __restrict__ rec,
                            const int* __restrict__ src, const int* __restrict__ dst,
                            int* __restrict__ gcur, int* __restrict__ pck,
                            int n, int ne, int npart) {
  int b = (int)blockIdx.x;
  if (b < npart) part_body(src, dst, gcur, pck, ne, b);
  else           prep_body(h, tax, whw, af, bf, rec, n, b - npart);
}

// One block per coarse bucket: exact CSR via LDS hist + scan.
__global__ void k_finesort(const int* __restrict__ pck, const int* __restrict__ gcur,
                           int* __restrict__ off, int* __restrict__ srcs,
                           int n, int nb) {
  __shared__ int s_hist[512];
  __shared__ int s_scan[512];
  __shared__ int s_pair[256];
  __shared__ int s_red[256];
  int b = blockIdx.x;
  int t = threadIdx.x;
  int cnt = gcur[b];
  int gbase = b * CAP;
  s_red[t] = (t < b && t < nb) ? gcur[t] : 0;
  s_hist[t] = 0; s_hist[t + 256] = 0;
  __syncthreads();
  for (int s = 128; s; s >>= 1) {
    if (t < s) s_red[t] += s_red[t + s];
    __syncthreads();
  }
  int base = s_red[0];
  for (int i = t; i < cnt; i += 256)
    atomicAdd(&s_hist[pck[gbase + i] & 511], 1);
  __syncthreads();
  int c0 = s_hist[2 * t], c1 = s_hist[2 * t + 1];
  int v = c0 + c1;
  s_pair[t] = v;
  __syncthreads();
  for (int s = 1; s < 256; s <<= 1) {
    int a = (t >= s) ? s_pair[t - s] : 0;
    __syncthreads();
    s_pair[t] += a;
    __syncthreads();
  }
  int pex = s_pair[t] - v;
  s_scan[2 * t] = pex;
  s_scan[2 * t + 1] = pex + c0;
  __syncthreads();
  int d0 = (b << 9) + 2 * t;
  if (d0 < n) off[d0] = base + s_scan[2 * t];
  if (d0 + 1 < n) off[d0 + 1] = base + s_scan[2 * t + 1];
  if (b == nb - 1 && t == 0) off[n] = base + cnt;
  s_hist[2 * t] = s_scan[2 * t];
  s_hist[2 * t + 1] = s_scan[2 * t + 1];
  __syncthreads();
  for (int i = t; i < cnt; i += 256) {
    int p = pck[gbase + i];
    int rank = atomicAdd(&s_hist[p & 511], 1);
    srcs[base + rank] = p >> 9;
  }
}

// One 16-lane group per dst node (4 nodes/wave), pair-unrolled 3-stage
// software pipeline: srcs read 2 pairs ahead, rec/af issued 1 pair ahead,
// compute on current pair. Steady-state 8 rec-gathers in flight per wave
// (2x the prior version). Invalid tail edges are neutralized branchlessly
// by clamping p/wf to -1e30 (exp2 -> 0) after the rowsum.
__launch_bounds__(256)
__global__ void k_fused(const uint4* __restrict__ rec,
                        const float* __restrict__ af, const float* __restrict__ bf,
                        const int* __restrict__ off, const int* __restrict__ srcs,
                        unsigned short* __restrict__ z, int n) {
  int d = (int)((blockIdx.x * blockDim.x + threadIdx.x) >> 4);
  int q = threadIdx.x & 15;
  if (d >= n) return;
  // dst side needs only its tax half: 8B instead of 16B.
  uint2 rd = *(const uint2*)((const char*)rec + ((((size_t)d << 4) + q) << 4));
  half2v d01 = __builtin_bit_cast(half2v, rd.x);
  half2v d23 = __builtin_bit_cast(half2v, rd.y);
  float bfd = bf[d];
  int beg = off[d], end = off[d + 1];
  float sf = 0.f, st = 0.f, mt = NEG_BIG;
  float zf0 = 0.f, zf1 = 0.f, zf2 = 0.f, zf3 = 0.f;
  float zt0 = 0.f, zt1 = 0.f, zt2 = 0.f, zt3 = 0.f;
  // ---- pipeline prologue ----
  int s0 = (beg     < end) ? srcs[beg]     : 0;
  int s1 = (beg + 1 < end) ? srcs[beg + 1] : 0;
  uint4 r0 = rec[((size_t)s0 << 4) + q];
  float a0 = af[s0];
  uint4 r1 = rec[((size_t)s1 << 4) + q];
  float a1 = af[s1];
  int s2 = (beg + 2 < end) ? srcs[beg + 2] : 0;
  int s3 = (beg + 3 < end) ? srcs[beg + 3] : 0;
  for (int i = beg; i < end; i += 2) {
    // stage B: issue next pair's gathers (addresses ready from last iter)
    uint4 rn0 = rec[((size_t)s2 << 4) + q];
    float an0 = af[s2];
    uint4 rn1 = rec[((size_t)s3 << 4) + q];
    float an1 = af[s3];
    // stage A: read srcs two pairs ahead (sequential, cache-hot)
    int s4 = (i + 4 < end) ? srcs[i + 4] : 0;
    int s5 = (i + 5 < end) ? srcs[i + 5] : 0;
    // stage C: compute current pair
    half2v t01a = __builtin_bit_cast(half2v, r0.x);
    half2v t23a = __builtin_bit_cast(half2v, r0.y);
    half2v h01a = __builtin_bit_cast(half2v, r0.z);
    half2v h23a = __builtin_bit_cast(half2v, r0.w);
    half2v t01b = __builtin_bit_cast(half2v, r1.x);
    half2v t23b = __builtin_bit_cast(half2v, r1.y);
    half2v h01b = __builtin_bit_cast(half2v, r1.z);
    half2v h23b = __builtin_bit_cast(half2v, r1.w);
    float p0 = fdot2(t23a, d23, fdot2(t01a, d01, 0.f)) * LOG2E;
    float p1 = fdot2(t23b, d23, fdot2(t01b, d01, 0.f)) * LOG2E;
    rowsum16x2(p0, p1);
    float wf0 = a0 + bfd;
    wf0 = (wf0 > 0.f) ? wf0 : NEG_SLOPE * wf0;
    float wf1 = a1 + bfd;
    wf1 = (wf1 > 0.f) ? wf1 : NEG_SLOPE * wf1;
    if (i + 1 >= end) { p1 = -1e30f; wf1 = -1e30f; }  // tail edge -> exp2 = 0
    float ef0 = fexp2(wf0), ef1 = fexp2(wf1);
    sf += ef0 + ef1;
    zf0 = fmaf((float)h01b[0], ef1, fmaf((float)h01a[0], ef0, zf0));
    zf1 = fmaf((float)h01b[1], ef1, fmaf((float)h01a[1], ef0, zf1));
    zf2 = fmaf((float)h23b[0], ef1, fmaf((float)h23a[0], ef0, zf2));
    zf3 = fmaf((float)h23b[1], ef1, fmaf((float)h23a[1], ef0, zf3));
    float pm0 = p0 - mt;
    if (pm0 > 60.f) {                 // rare: first edge / new-max-by-far
      float sc = fexp2(-pm0);         // ==0 when mt==NEG_BIG
      st *= sc;
      zt0 *= sc; zt1 *= sc; zt2 *= sc; zt3 *= sc;
      mt = p0; pm0 = 0.f;
    }
    float et0 = fexp2(pm0);
    st += et0;
    zt0 = fmaf((float)h01a[0], et0, zt0);
    zt1 = fmaf((float)h01a[1], et0, zt1);
    zt2 = fmaf((float)h23a[0], et0, zt2);
    zt3 = fmaf((float)h23a[1], et0, zt3);
    float pm1 = p1 - mt;
    if (pm1 > 60.f) {
      float sc = fexp2(-pm1);
      st *= sc;
      zt0 *= sc; zt1 *= sc; zt2 *= sc; zt3 *= sc;
      mt = p1; pm1 = 0.f;
    }
    float et1 = fexp2(pm1);
    st += et1;
    zt0 = fmaf((float)h01b[0], et1, zt0);
    zt1 = fmaf((float)h01b[1], et1, zt1);
    zt2 = fmaf((float)h23b[0], et1, zt2);
    zt3 = fmaf((float)h23b[1], et1, zt3);
    // rotate pipeline
    r0 = rn0; r1 = rn1; a0 = an0; a1 = an1;
    s2 = s4;  s3 = s5;
  }
  float4 zv = make_float4(0.f, 0.f, 0.f, 0.f);
  if (end > beg) {
    float rf = ETA / sf, rt = (1.f - ETA) / st;
    zv.x = rf * zf0 + rt * zt0;
    zv.y = rf * zf1 + rt * zt1;
    zv.z = rf * zf2 + rt * zt2;
    zv.w = rf * zf3 + rt * zt3;
  }
  uint2 zo;
  zo.x = pack2(zv.x, zv.y);
  zo.y = pack2(zv.z, zv.w);
  ((uint2*)(z + (size_t)d * 64))[q] = zo;
}

// out[n][j] = sum_k z[n][k] * W[j][k] + b[j], z in f16.
__launch_bounds__(256)
__global__ void k_out_gemm(const unsigned short* __restrict__ z,
                           const float* __restrict__ W,
                           const float* __restrict__ b, float* __restrict__ out, int n) {
  int t = threadIdx.x;
  int j = t & 63, nl = t >> 6;
  float wreg[64];
#pragma unroll
  for (int i = 0; i < 16; ++i)
    ((float4*)wreg)[i] = ((const float4*)(W + (size_t)j * 64))[i];
  float bias = b[j];
  int stride = gridDim.x * 4;
  for (int node = blockIdx.x * 4 + nl; node < n; node += stride) {
    float zv = (float)__builtin_bit_cast(_Float16, z[(size_t)node * 64 + j]);
    float acc = bias;
#pragma unroll
    for (int k = 0; k < 64; ++k)
      acc += __shfl(zv, k) * wreg[k];
    out[(size_t)node * 64 + j] = acc;
  }
}

extern "C" void kernel_launch(void* const* d_in, const int* in_sizes, int n_in,
                              void* d_out, int out_size, void* d_ws, size_t ws_size,
                              hipStream_t stream) {
  const float* h   = (const float*)d_in[0];
  const float* tax = (const float*)d_in[1];
  const int*   src = (const int*)d_in[2];
  const int*   dst = (const int*)d_in[3];
  const float* whw = (const float*)d_in[4];
  const float* Ww  = (const float*)d_in[5];
  const float* Wb  = (const float*)d_in[6];
  float* out = (float*)d_out;
  int n  = in_sizes[0] / 64;
  int ne = in_sizes[2];
  int nb = (n + 511) >> 9;  // coarse buckets (196 for n=100k); nb<=256

  // Workspace layout (4-byte words; rec aligned to 16 B):
  float* af   = (float*)d_ws;               // n
  float* bf   = af + n;                     // n
  int*   off  = (int*)(bf + n);             // n+2
  int*   srcs = off + n + 2;                // ne
  int*   gcur = srcs + ne;                  // 256
  size_t w = (size_t)(2 * n) + (n + 2) + ne + 256;
  w = (w + 3) & ~(size_t)3;                 // 16B-align
  unsigned short* z = (unsigned short*)((int*)d_ws + w);  // n*64 u16
  uint4* rec = (uint4*)(z + (size_t)n * 64);              // n*16 uint4
  // Packed sort plane aliases z (consumed by k_finesort before z written):
  int* pck = (int*)z;                       // nb*CAP*4B (8MB) <= n*128B (12.8MB)

  int nprep = (n * 16 + 255) / 256;
  int npart = (ne + PCHUNK - 1) / PCHUNK;
  int bw    = (n + 15) / 16;

  hipMemsetAsync(gcur, 0, 256 * sizeof(int), stream);
  k_prep_part<<<npart + nprep, 256, 0, stream>>>(h, tax, whw, af, bf, rec,
                                                 src, dst, gcur, pck, n, ne, npart);
  k_finesort<<<nb, 256, 0, stream>>>(pck, gcur, off, srcs, n, nb);
  k_fused<<<bw, 256, 0, stream>>>(rec, af, bf, off, srcs, z, n);
  k_out_gemm<<<1024, 256, 0, stream>>>(z, Ww, Wb, out, n);
}

// Round 3
// 259.110 us; speedup vs baseline: 1.2560x; 1.2336x over previous
//
#include <hip/hip_runtime.h>

#define NEG_SLOPE 0.01f
#define ETA 0.5f
#define NEG_BIG -3.402823466e38f
#define LOG2E 1.4426950408889634f
#define PCHUNK 4096   // edges per partition block
#define CAP 10240     // per-coarse-bucket capacity (mean 8192 + 22 sigma)

typedef _Float16 half2v __attribute__((ext_vector_type(2)));
typedef _Float16 half8v __attribute__((ext_vector_type(8)));
typedef float f32x4v __attribute__((ext_vector_type(4)));

#if defined(__has_builtin)
#if __has_builtin(__builtin_amdgcn_fdot2)
#define HAVE_FDOT2 1
#endif
#if __has_builtin(__builtin_amdgcn_exp2f)
#define HAVE_EXP2 1
#endif
#if __has_builtin(__builtin_amdgcn_update_dpp)
#define HAVE_DPP 1
#endif
#if __has_builtin(__builtin_amdgcn_mfma_f32_16x16x32_f16)
#define HAVE_MFMA16 1
#endif
#endif

__device__ __forceinline__ float fdot2(half2v a, half2v b, float c) {
#ifdef HAVE_FDOT2
  return __builtin_amdgcn_fdot2(a, b, c, false);
#else
  return (float)a[0] * (float)b[0] + (float)a[1] * (float)b[1] + c;
#endif
}

__device__ __forceinline__ unsigned pack2(float x, float y) {
  half2v h = {( _Float16)x, (_Float16)y};
  return __builtin_bit_cast(unsigned, h);
}

// exp2 (inputs are pre-scaled into log2 domain)
__device__ __forceinline__ float fexp2(float x) {
#ifdef HAVE_EXP2
  return __builtin_amdgcn_exp2f(x);
#else
  return __expf(x * 0.6931471805599453f);
#endif
}

// Interleaved dual 16-lane row-sum (VALU pipe, no LDS); interleaving the two
// chains hides the DPP->add dependency latency.
__device__ __forceinline__ void rowsum16x2(float& x, float& y) {
#ifdef HAVE_DPP
#define DPPADD(v, ctl)                                                        \
  v += __builtin_bit_cast(float, __builtin_amdgcn_update_dpp(                 \
         0, __builtin_bit_cast(int, v), ctl, 0xf, 0xf, true))
  DPPADD(x, 0x121); DPPADD(y, 0x121);   // row_ror:1
  DPPADD(x, 0x122); DPPADD(y, 0x122);   // row_ror:2
  DPPADD(x, 0x124); DPPADD(y, 0x124);   // row_ror:4
  DPPADD(x, 0x128); DPPADD(y, 0x128);   // row_ror:8
#undef DPPADD
#else
#pragma unroll
  for (int o = 1; o < 16; o <<= 1) {
    x += __shfl_xor(x, o);
    y += __shfl_xor(y, o);
  }
#endif
}

// ---- prep: node dots af/bf (pre-scaled by log2e) + interleaved f16 record ----
__device__ __forceinline__ void prep_body(const float* __restrict__ h,
                                          const float* __restrict__ tax,
                                          const float* __restrict__ whw,
                                          float* __restrict__ af, float* __restrict__ bf,
                                          uint4* __restrict__ rec, int n, int blk) {
  int gid = blk * 256 + (int)threadIdx.x;
  int node = gid >> 4, lane = gid & 15;
  if (node >= n) return;
  float4 x  = ((const float4*)(h + (size_t)node * 64))[lane];
  float4 tx = ((const float4*)(tax + (size_t)node * 64))[lane];
  float4 wa = ((const float4*)whw)[lane];
  float4 wb = ((const float4*)(whw + 64))[lane];
  uint4 r;
  r.x = pack2(tx.x, tx.y);
  r.y = pack2(tx.z, tx.w);
  r.z = pack2(x.x, x.y);
  r.w = pack2(x.z, x.w);
  rec[((size_t)node << 4) + lane] = r;
  float pa = x.x * wa.x + x.y * wa.y + x.z * wa.z + x.w * wa.w;
  float pb = x.x * wb.x + x.y * wb.y + x.z * wb.z + x.w * wb.w;
#pragma unroll
  for (int o = 8; o; o >>= 1) {
    pa += __shfl_xor(pa, o);
    pb += __shfl_xor(pb, o);
  }
  // leaky_relu(c*x) == c*leaky_relu(x) for c>0, so pre-scaling into the
  // exp2 domain is exact w.r.t. the lrelu and the softmax ratios.
  if (lane == 0) { af[node] = pa * LOG2E; bf[node] = pb * LOG2E; }
}

// ---- coarse partition by bucket = dst>>9 ----
__device__ __forceinline__ void part_body(const int* __restrict__ src,
                                          const int* __restrict__ dst,
                                          int* __restrict__ gcur, int* __restrict__ pck,
                                          int ne, int blk) {
  __shared__ int s_hist[256];
  __shared__ int s_res[256];
  __shared__ int s_cur[256];
  int t = threadIdx.x;
  int base = blk * PCHUNK;
  int cnt = ne - base; if (cnt > PCHUNK) cnt = PCHUNK;
  s_hist[t] = 0;
  __syncthreads();
  for (int i = t; i < cnt; i += 256)
    atomicAdd(&s_hist[dst[base + i] >> 9], 1);
  __syncthreads();
  int v = s_hist[t];
  if (v > 0) s_res[t] = atomicAdd(&gcur[t], v);
  s_cur[t] = 0;
  __syncthreads();
  for (int i = t; i < cnt; i += 256) {
    int d = dst[base + i];
    int r = d >> 9;
    int g = s_res[r] + atomicAdd(&s_cur[r], 1);
    if (g < CAP)
      pck[r * CAP + g] = (src[base + i] << 9) | (d & 511);
  }
}

// Fused prep + partition. Partition blocks FIRST so the latency/atomic-bound
// partition overlaps with prep's BW-bound streaming. gcur zeroed by memset.
__global__ void k_prep_part(const float* __restrict__ h, const float* __restrict__ tax,
                            const float* __restrict__ whw,
                            float* __restrict__ af, float* __restrict__ bf,
                            uint4* __restrict__ rec,
                            const int* __restrict__ src, const int* __restrict__ dst,
                            int* __restrict__ gcur, int* __restrict__ pck,
                            int n, int ne, int npart) {
  int b = (int)blockIdx.x;
  if (b < npart) part_body(src, dst, gcur, pck, ne, b);
  else           prep_body(h, tax, whw, af, bf, rec, n, b - npart);
}

// One block per coarse bucket: exact CSR via LDS hist + scan.
__global__ void k_finesort(const int* __restrict__ pck, const int* __restrict__ gcur,
                           int* __restrict__ off, int* __restrict__ srcs,
                           int n, int nb) {
  __shared__ int s_hist[512];
  __shared__ int s_scan[512];
  __shared__ int s_pair[256];
  __shared__ int s_red[256];
  int b = blockIdx.x;
  int t = threadIdx.x;
  int cnt = gcur[b];
  int gbase = b * CAP;
  s_red[t] = (t < b && t < nb) ? gcur[t] : 0;
  s_hist[t] = 0; s_hist[t + 256] = 0;
  __syncthreads();
  for (int s = 128; s; s >>= 1) {
    if (t < s) s_red[t] += s_red[t + s];
    __syncthreads();
  }
  int base = s_red[0];
  for (int i = t; i < cnt; i += 256)
    atomicAdd(&s_hist[pck[gbase + i] & 511], 1);
  __syncthreads();
  int c0 = s_hist[2 * t], c1 = s_hist[2 * t + 1];
  int v = c0 + c1;
  s_pair[t] = v;
  __syncthreads();
  for (int s = 1; s < 256; s <<= 1) {
    int a = (t >= s) ? s_pair[t - s] : 0;
    __syncthreads();
    s_pair[t] += a;
    __syncthreads();
  }
  int pex = s_pair[t] - v;
  s_scan[2 * t] = pex;
  s_scan[2 * t + 1] = pex + c0;
  __syncthreads();
  int d0 = (b << 9) + 2 * t;
  if (d0 < n) off[d0] = base + s_scan[2 * t];
  if (d0 + 1 < n) off[d0 + 1] = base + s_scan[2 * t + 1];
  if (b == nb - 1 && t == 0) off[n] = base + cnt;
  s_hist[2 * t] = s_scan[2 * t];
  s_hist[2 * t + 1] = s_scan[2 * t + 1];
  __syncthreads();
  for (int i = t; i < cnt; i += 256) {
    int p = pck[gbase + i];
    int rank = atomicAdd(&s_hist[p & 511], 1);
    srcs[base + rank] = p >> 9;
  }
}

// One 16-lane group per dst node (4 nodes/wave), pair-unrolled 3-stage
// software pipeline: srcs read 2 pairs ahead, rec/af issued 1 pair ahead,
// compute on current pair. Steady-state 8 rec-gathers in flight per wave.
// Invalid tail edges are neutralized branchlessly by clamping p/wf to
// -1e30 (exp2 -> 0) after the rowsum.
__launch_bounds__(256)
__global__ void k_fused(const uint4* __restrict__ rec,
                        const float* __restrict__ af, const float* __restrict__ bf,
                        const int* __restrict__ off, const int* __restrict__ srcs,
                        unsigned short* __restrict__ z, int n) {
  int d = (int)((blockIdx.x * blockDim.x + threadIdx.x) >> 4);
  int q = threadIdx.x & 15;
  if (d >= n) return;
  // dst side needs only its tax half: 8B instead of 16B.
  uint2 rd = *(const uint2*)((const char*)rec + ((((size_t)d << 4) + q) << 4));
  half2v d01 = __builtin_bit_cast(half2v, rd.x);
  half2v d23 = __builtin_bit_cast(half2v, rd.y);
  float bfd = bf[d];
  int beg = off[d], end = off[d + 1];
  float sf = 0.f, st = 0.f, mt = NEG_BIG;
  float zf0 = 0.f, zf1 = 0.f, zf2 = 0.f, zf3 = 0.f;
  float zt0 = 0.f, zt1 = 0.f, zt2 = 0.f, zt3 = 0.f;
  // ---- pipeline prologue ----
  int s0 = (beg     < end) ? srcs[beg]     : 0;
  int s1 = (beg + 1 < end) ? srcs[beg + 1] : 0;
  uint4 r0 = rec[((size_t)s0 << 4) + q];
  float a0 = af[s0];
  uint4 r1 = rec[((size_t)s1 << 4) + q];
  float a1 = af[s1];
  int s2 = (beg + 2 < end) ? srcs[beg + 2] : 0;
  int s3 = (beg + 3 < end) ? srcs[beg + 3] : 0;
  for (int i = beg; i < end; i += 2) {
    // stage B: issue next pair's gathers (addresses ready from last iter)
    uint4 rn0 = rec[((size_t)s2 << 4) + q];
    float an0 = af[s2];
    uint4 rn1 = rec[((size_t)s3 << 4) + q];
    float an1 = af[s3];
    // stage A: read srcs two pairs ahead (sequential, cache-hot)
    int s4 = (i + 4 < end) ? srcs[i + 4] : 0;
    int s5 = (i + 5 < end) ? srcs[i + 5] : 0;
    // stage C: compute current pair
    half2v t01a = __builtin_bit_cast(half2v, r0.x);
    half2v t23a = __builtin_bit_cast(half2v, r0.y);
    half2v h01a = __builtin_bit_cast(half2v, r0.z);
    half2v h23a = __builtin_bit_cast(half2v, r0.w);
    half2v t01b = __builtin_bit_cast(half2v, r1.x);
    half2v t23b = __builtin_bit_cast(half2v, r1.y);
    half2v h01b = __builtin_bit_cast(half2v, r1.z);
    half2v h23b = __builtin_bit_cast(half2v, r1.w);
    float p0 = fdot2(t23a, d23, fdot2(t01a, d01, 0.f)) * LOG2E;
    float p1 = fdot2(t23b, d23, fdot2(t01b, d01, 0.f)) * LOG2E;
    rowsum16x2(p0, p1);
    float wf0 = a0 + bfd;
    wf0 = (wf0 > 0.f) ? wf0 : NEG_SLOPE * wf0;
    float wf1 = a1 + bfd;
    wf1 = (wf1 > 0.f) ? wf1 : NEG_SLOPE * wf1;
    if (i + 1 >= end) { p1 = -1e30f; wf1 = -1e30f; }  // tail edge -> exp2 = 0
    float ef0 = fexp2(wf0), ef1 = fexp2(wf1);
    sf += ef0 + ef1;
    zf0 = fmaf((float)h01b[0], ef1, fmaf((float)h01a[0], ef0, zf0));
    zf1 = fmaf((float)h01b[1], ef1, fmaf((float)h01a[1], ef0, zf1));
    zf2 = fmaf((float)h23b[0], ef1, fmaf((float)h23a[0], ef0, zf2));
    zf3 = fmaf((float)h23b[1], ef1, fmaf((float)h23a[1], ef0, zf3));
    float pm0 = p0 - mt;
    if (pm0 > 60.f) {                 // rare: first edge / new-max-by-far
      float sc = fexp2(-pm0);         // ==0 when mt==NEG_BIG
      st *= sc;
      zt0 *= sc; zt1 *= sc; zt2 *= sc; zt3 *= sc;
      mt = p0; pm0 = 0.f;
    }
    float et0 = fexp2(pm0);
    st += et0;
    zt0 = fmaf((float)h01a[0], et0, zt0);
    zt1 = fmaf((float)h01a[1], et0, zt1);
    zt2 = fmaf((float)h23a[0], et0, zt2);
    zt3 = fmaf((float)h23a[1], et0, zt3);
    float pm1 = p1 - mt;
    if (pm1 > 60.f) {
      float sc = fexp2(-pm1);
      st *= sc;
      zt0 *= sc; zt1 *= sc; zt2 *= sc; zt3 *= sc;
      mt = p1; pm1 = 0.f;
    }
    float et1 = fexp2(pm1);
    st += et1;
    zt0 = fmaf((float)h01b[0], et1, zt0);
    zt1 = fmaf((float)h01b[1], et1, zt1);
    zt2 = fmaf((float)h23b[0], et1, zt2);
    zt3 = fmaf((float)h23b[1], et1, zt3);
    // rotate pipeline
    r0 = rn0; r1 = rn1; a0 = an0; a1 = an1;
    s2 = s4;  s3 = s5;
  }
  float4 zv = make_float4(0.f, 0.f, 0.f, 0.f);
  if (end > beg) {
    float rf = ETA / sf, rt = (1.f - ETA) / st;
    zv.x = rf * zf0 + rt * zt0;
    zv.y = rf * zf1 + rt * zt1;
    zv.z = rf * zf2 + rt * zt2;
    zv.w = rf * zf3 + rt * zt3;
  }
  uint2 zo;
  zo.x = pack2(zv.x, zv.y);
  zo.y = pack2(zv.z, zv.w);
  ((uint2*)(z + (size_t)d * 64))[q] = zo;
}

// out = z @ W^T + b via MFMA. One wave per 16-node tile, all 64 output cols.
// A = z tile (f16, native layout: lane holds row l&15, k = (l>>4)*8..+7).
// B = W^T with W split into f16 hi+lo (W = Whi + Wlo) so accuracy stays at
// the f32-weight level; both parts accumulate into the same f32 acc.
// C/D layout (m89-verified): col = lane&15, row = (lane>>4)*4 + reg.
#ifdef HAVE_MFMA16
__launch_bounds__(256)
__global__ void k_out_gemm(const unsigned short* __restrict__ z,
                           const float* __restrict__ W,
                           const float* __restrict__ b, float* __restrict__ out, int n) {
  int l = threadIdx.x & 63;
  int wv = threadIdx.x >> 6;
  int c16 = l & 15;   // A-row / B-col / D-col within tile
  int seg = l >> 4;   // k-segment selector
  // B fragments: j = jt*16 + c16; per K-step ks, k = ks*32 + seg*8 + [0..7]
  half8v bh[4][2], bl[4][2];
#pragma unroll
  for (int jt = 0; jt < 4; ++jt) {
    const float* wr = W + (size_t)(jt * 16 + c16) * 64 + seg * 8;
#pragma unroll
    for (int ks = 0; ks < 2; ++ks) {
      const float* wk = wr + ks * 32;
#pragma unroll
      for (int e = 0; e < 8; ++e) {
        float wvv = wk[e];
        _Float16 hi = (_Float16)wvv;
        bh[jt][ks][e] = hi;
        bl[jt][ks][e] = (_Float16)(wvv - (float)hi);
      }
    }
  }
  float bias0 = b[c16], bias1 = b[16 + c16], bias2 = b[32 + c16], bias3 = b[48 + c16];
  const half8v* z8 = (const half8v*)z;  // 8 f16 (16B) chunks; 8 chunks per node
  int tiles = (n + 15) >> 4;
  int nw = (int)gridDim.x * 4;
  for (int t = (int)blockIdx.x * 4 + wv; t < tiles; t += nw) {
    int base = t << 4;
    int arow = base + c16;
    size_t zi = (size_t)(arow < n ? arow : n - 1) * 8 + seg;
    half8v a0 = z8[zi];
    half8v a1 = z8[zi + 4];
    f32x4v acc0 = {bias0, bias0, bias0, bias0};
    f32x4v acc1 = {bias1, bias1, bias1, bias1};
    f32x4v acc2 = {bias2, bias2, bias2, bias2};
    f32x4v acc3 = {bias3, bias3, bias3, bias3};
    acc0 = __builtin_amdgcn_mfma_f32_16x16x32_f16(a0, bh[0][0], acc0, 0, 0, 0);
    acc1 = __builtin_amdgcn_mfma_f32_16x16x32_f16(a0, bh[1][0], acc1, 0, 0, 0);
    acc2 = __builtin_amdgcn_mfma_f32_16x16x32_f16(a0, bh[2][0], acc2, 0, 0, 0);
    acc3 = __builtin_amdgcn_mfma_f32_16x16x32_f16(a0, bh[3][0], acc3, 0, 0, 0);
    acc0 = __builtin_amdgcn_mfma_f32_16x16x32_f16(a1, bh[0][1], acc0, 0, 0, 0);
    acc1 = __builtin_amdgcn_mfma_f32_16x16x32_f16(a1, bh[1][1], acc1, 0, 0, 0);
    acc2 = __builtin_amdgcn_mfma_f32_16x16x32_f16(a1, bh[2][1], acc2, 0, 0, 0);
    acc3 = __builtin_amdgcn_mfma_f32_16x16x32_f16(a1, bh[3][1], acc3, 0, 0, 0);
    acc0 = __builtin_amdgcn_mfma_f32_16x16x32_f16(a0, bl[0][0], acc0, 0, 0, 0);
    acc1 = __builtin_amdgcn_mfma_f32_16x16x32_f16(a0, bl[1][0], acc1, 0, 0, 0);
    acc2 = __builtin_amdgcn_mfma_f32_16x16x32_f16(a0, bl[2][0], acc2, 0, 0, 0);
    acc3 = __builtin_amdgcn_mfma_f32_16x16x32_f16(a0, bl[3][0], acc3, 0, 0, 0);
    acc0 = __builtin_amdgcn_mfma_f32_16x16x32_f16(a1, bl[0][1], acc0, 0, 0, 0);
    acc1 = __builtin_amdgcn_mfma_f32_16x16x32_f16(a1, bl[1][1], acc1, 0, 0, 0);
    acc2 = __builtin_amdgcn_mfma_f32_16x16x32_f16(a1, bl[2][1], acc2, 0, 0, 0);
    acc3 = __builtin_amdgcn_mfma_f32_16x16x32_f16(a1, bl[3][1], acc3, 0, 0, 0);
#pragma unroll
    for (int r = 0; r < 4; ++r) {
      int nrow = base + seg * 4 + r;
      if (nrow < n) {
        float* o = out + (size_t)nrow * 64 + c16;
        o[0]  = acc0[r];
        o[16] = acc1[r];
        o[32] = acc2[r];
        o[48] = acc3[r];
      }
    }
  }
}
#else
// Fallback: per-node shfl broadcast (slow path; should not be used on gfx950).
__launch_bounds__(256)
__global__ void k_out_gemm(const unsigned short* __restrict__ z,
                           const float* __restrict__ W,
                           const float* __restrict__ b, float* __restrict__ out, int n) {
  int t = threadIdx.x;
  int j = t & 63, nl = t >> 6;
  float wreg[64];
#pragma unroll
  for (int i = 0; i < 16; ++i)
    ((float4*)wreg)[i] = ((const float4*)(W + (size_t)j * 64))[i];
  float bias = b[j];
  int stride = gridDim.x * 4;
  for (int node = blockIdx.x * 4 + nl; node < n; node += stride) {
    float zv = (float)__builtin_bit_cast(_Float16, z[(size_t)node * 64 + j]);
    float acc = bias;
#pragma unroll
    for (int k = 0; k < 64; ++k)
      acc += __shfl(zv, k) * wreg[k];
    out[(size_t)node * 64 + j] = acc;
  }
}
#endif

extern "C" void kernel_launch(void* const* d_in, const int* in_sizes, int n_in,
                              void* d_out, int out_size, void* d_ws, size_t ws_size,
                              hipStream_t stream) {
  const float* h   = (const float*)d_in[0];
  const float* tax = (const float*)d_in[1];
  const int*   src = (const int*)d_in[2];
  const int*   dst = (const int*)d_in[3];
  const float* whw = (const float*)d_in[4];
  const float* Ww  = (const float*)d_in[5];
  const float* Wb  = (const float*)d_in[6];
  float* out = (float*)d_out;
  int n  = in_sizes[0] / 64;
  int ne = in_sizes[2];
  int nb = (n + 511) >> 9;  // coarse buckets (196 for n=100k); nb<=256

  // Workspace layout (4-byte words; rec aligned to 16 B):
  float* af   = (float*)d_ws;               // n
  float* bf   = af + n;                     // n
  int*   off  = (int*)(bf + n);             // n+2
  int*   srcs = off + n + 2;                // ne
  int*   gcur = srcs + ne;                  // 256
  size_t w = (size_t)(2 * n) + (n + 2) + ne + 256;
  w = (w + 3) & ~(size_t)3;                 // 16B-align
  unsigned short* z = (unsigned short*)((int*)d_ws + w);  // n*64 u16
  uint4* rec = (uint4*)(z + (size_t)n * 64);              // n*16 uint4
  // Packed sort plane aliases z (consumed by k_finesort before z written):
  int* pck = (int*)z;                       // nb*CAP*4B (8MB) <= n*128B (12.8MB)

  int nprep = (n * 16 + 255) / 256;
  int npart = (ne + PCHUNK - 1) / PCHUNK;
  int bw    = (n + 15) / 16;

  hipMemsetAsync(gcur, 0, 256 * sizeof(int), stream);
  k_prep_part<<<npart + nprep, 256, 0, stream>>>(h, tax, whw, af, bf, rec,
                                                 src, dst, gcur, pck, n, ne, npart);
  k_finesort<<<nb, 256, 0, stream>>>(pck, gcur, off, srcs, n, nb);
  k_fused<<<bw, 256, 0, stream>>>(rec, af, bf, off, srcs, z, n);
  k_out_gemm<<<1024, 256, 0, stream>>>(z, Ww, Wb, out, n);
}